// Round 4
// baseline (973.226 us; speedup 1.0000x reference)
//
#include <hip/hip_runtime.h>
#include <math.h>

#define FIN  1433
#define HID  16
#define NCLS 7
#define BM   128
#define BK   32
#define KS   4          // split-K slices
#define KT_TOTAL 45     // ceil(1433/32)

// ---------------- K1: split-K tiled dual GEMM ----------------
// C[n x 32] = x[n x 1433] @ [w_rel1 | w_root1]; grid (ceil(n/128), KS).
// Slice s accumulates k-tiles [45*s/4, 45*(s+1)/4) into pP[s], pA[s].
// LDS x-tile XOR-swizzled (write (c,r) -> xs[c*128+(r^c)]), reads are
// float4 with a static component unpermute. Register prefetch overlaps
// next tile's global loads with current compute.
__global__ __launch_bounds__(256) void k1_gemm(
    const float* __restrict__ x,
    const float* __restrict__ w_root, const float* __restrict__ w_rel,
    const float* __restrict__ b_rel,
    float* __restrict__ pbase, float* __restrict__ abase,
    size_t seg_elems, int n) {
  __shared__ float xs[BK * BM];
  __shared__ float ws[BK * 32];

  const int tid   = threadIdx.x;
  const int row0  = blockIdx.x * BM;
  const int slice = blockIdx.y;
  const int cg    = tid & 7;
  const int rg    = tid >> 3;
  const int c0    = cg * 4;
  const int r0    = rg * 4;

  const int kt_beg = (KT_TOTAL * slice) / KS;
  const int kt_end = (KT_TOTAL * (slice + 1)) / KS;

  float acc[4][4];
#pragma unroll
  for (int i = 0; i < 4; ++i)
#pragma unroll
    for (int j = 0; j < 4; ++j) acc[i][j] = 0.f;

  float xreg[16], wreg[4];
  auto prefetch = [&](int kt) {
    const int k0 = kt * BK;
#pragma unroll
    for (int i = 0; i < 16; ++i) {
      int idx = i * 256 + tid;
      int r = idx >> 5, c = idx & 31;
      int gr = row0 + r, gk = k0 + c;
      xreg[i] = (gr < n && gk < FIN) ? x[(size_t)gr * FIN + gk] : 0.f;
    }
#pragma unroll
    for (int i = 0; i < 4; ++i) {
      int idx = i * 256 + tid;
      int kk = idx >> 5, c = idx & 31;
      int gk = k0 + kk;
      float v = 0.f;
      if (gk < FIN) v = (c < HID) ? w_rel[gk * HID + c] : w_root[gk * HID + (c - HID)];
      wreg[i] = v;
    }
  };

  prefetch(kt_beg);
  for (int kt = kt_beg; kt < kt_end; ++kt) {
    __syncthreads();
#pragma unroll
    for (int i = 0; i < 16; ++i) {
      int idx = i * 256 + tid;
      int r = idx >> 5, c = idx & 31;
      xs[c * BM + (r ^ c)] = xreg[i];
    }
#pragma unroll
    for (int i = 0; i < 4; ++i) {
      int idx = i * 256 + tid;
      int kk = idx >> 5, c = idx & 31;
      ws[kk * 32 + c] = wreg[i];
    }
    __syncthreads();
    if (kt + 1 < kt_end) prefetch(kt + 1);
#pragma unroll
    for (int kk = 0; kk < BK; ++kk) {
      float4 xv = *(const float4*)&xs[kk * BM + ((r0 ^ kk) & ~3)];
      float4 wv = *(const float4*)&ws[kk * 32 + c0];
      float comp[4] = {xv.x, xv.y, xv.z, xv.w};
      const int p = kk & 3;
      float xa[4] = {comp[0 ^ p], comp[1 ^ p], comp[2 ^ p], comp[3 ^ p]};
      float wa[4] = {wv.x, wv.y, wv.z, wv.w};
#pragma unroll
      for (int i = 0; i < 4; ++i)
#pragma unroll
        for (int j = 0; j < 4; ++j)
          acc[i][j] = fmaf(xa[i], wa[j], acc[i][j]);
    }
  }

  float* __restrict__ p_out = pbase + (size_t)slice * seg_elems;
  float* __restrict__ a_out = abase + (size_t)slice * seg_elems;
  if (cg < 4) {
#pragma unroll
    for (int i = 0; i < 4; ++i) {
      int gr = row0 + r0 + i;
      if (gr < n) {
        float4 v = {acc[i][0], acc[i][1], acc[i][2], acc[i][3]};
        *(float4*)&p_out[(size_t)gr * HID + c0] = v;
      }
    }
  } else {
    const int cb = c0 - HID;
    float b0 = 0.f, b1 = 0.f, b2v = 0.f, b3 = 0.f;
    if (slice == 0) { b0 = b_rel[cb]; b1 = b_rel[cb+1]; b2v = b_rel[cb+2]; b3 = b_rel[cb+3]; }
#pragma unroll
    for (int i = 0; i < 4; ++i) {
      int gr = row0 + r0 + i;
      if (gr < n) {
        float4 v = {acc[i][0] + b0, acc[i][1] + b1, acc[i][2] + b2v, acc[i][3] + b3};
        *(float4*)&a_out[(size_t)gr * HID + cb] = v;
      }
    }
  }
}

// KR: sum KS split-K partials into slice 0 (float4 granularity).
__global__ __launch_bounds__(256) void k_reduce(
    float* __restrict__ pbase, float* __restrict__ abase,
    size_t seg_elems, int n4) {
  int i = blockIdx.x * 256 + threadIdx.x;
  if (i >= n4) return;
  size_t s4 = seg_elems / 4;
  float4 a = ((const float4*)pbase)[i];
  float4 c = ((const float4*)abase)[i];
#pragma unroll
  for (int s = 1; s < KS; ++s) {
    float4 b = ((const float4*)pbase)[i + s * s4];
    float4 d = ((const float4*)abase)[i + s * s4];
    a.x += b.x; a.y += b.y; a.z += b.z; a.w += b.w;
    c.x += d.x; c.y += d.y; c.z += d.z; c.w += d.w;
  }
  ((float4*)pbase)[i] = a;
  ((float4*)abase)[i] = c;
}

// ---------------- edge bucketing (counting sort by dst) ----------------
__global__ __launch_bounds__(256) void k_zero(int* __restrict__ p, int n) {
  int i = blockIdx.x * 256 + threadIdx.x;
  if (i < n) p[i] = 0;
}

__global__ __launch_bounds__(256) void k_hist(
    const int* __restrict__ ei, int* __restrict__ hist, int nE) {
  int e = blockIdx.x * 256 + threadIdx.x;
  if (e >= nE) return;
  atomicAdd(hist + ei[nE + e], 1);
}

// Single-block exclusive scan over n counts -> offs, cur.
__global__ __launch_bounds__(1024) void k_scan(
    const int* __restrict__ hist, int* __restrict__ offs,
    int* __restrict__ cur, int n) {
  __shared__ int sums[1024];
  const int tid = threadIdx.x;
  const int per = (n + 1023) / 1024;
  const int beg = tid * per;
  const int end = min(beg + per, n);
  int s = 0;
  for (int i = beg; i < end; ++i) s += hist[i];
  sums[tid] = s;
  __syncthreads();
  for (int d = 1; d < 1024; d <<= 1) {
    int add = (tid >= d) ? sums[tid - d] : 0;
    __syncthreads();
    sums[tid] += add;
    __syncthreads();
  }
  int offset = sums[tid] - s;   // exclusive prefix of this thread's range
  for (int i = beg; i < end; ++i) {
    offs[i] = offset; cur[i] = offset;
    offset += hist[i];
  }
}

__global__ __launch_bounds__(256) void k_place(
    const int* __restrict__ ei, int* __restrict__ cur,
    int* __restrict__ sorted_src, int nE) {
  int e = blockIdx.x * 256 + threadIdx.x;
  if (e >= nE) return;
  int pos = atomicAdd(cur + ei[nE + e], 1);
  sorted_src[pos] = ei[e];
}

// KA1: 16 lanes per dst; agg[d][f] += sum_{j in bucket(d)} p1[src_j][f].
__global__ __launch_bounds__(256) void k_agg16(
    const int* __restrict__ sorted_src, const int* __restrict__ offs,
    const int* __restrict__ hist, const float* __restrict__ p1,
    float* __restrict__ agg, int n) {
  long long gt = (long long)blockIdx.x * 256 + threadIdx.x;
  int d = (int)(gt >> 4), f = (int)(gt & 15);
  if (d >= n) return;
  int base = offs[d], deg = hist[d];
  float acc = 0.f;
  for (int j = 0; j < deg; ++j) {
    int s = sorted_src[base + j];
    acc += p1[(size_t)s * HID + f];
  }
  agg[(size_t)d * HID + f] += acc;   // root part + bias already there
}

// KA2: 8 lanes per dst (7 used); out[d][f] += sum p2[src_j][f].
__global__ __launch_bounds__(256) void k_agg7(
    const int* __restrict__ sorted_src, const int* __restrict__ offs,
    const int* __restrict__ hist, const float* __restrict__ p2,
    float* __restrict__ out, int n) {
  long long gt = (long long)blockIdx.x * 256 + threadIdx.x;
  int d = (int)(gt >> 3), f = (int)(gt & 7);
  if (d >= n || f >= NCLS) return;
  int base = offs[d], deg = hist[d];
  float acc = 0.f;
  for (int j = 0; j < deg; ++j) {
    int s = sorted_src[base + j];
    acc += p2[(size_t)s * NCLS + f];
  }
  out[(size_t)d * NCLS + f] += acc;
}

// K3: ELU + dual 16x7 projection; out2 gets root part + bias.
__global__ __launch_bounds__(256) void k3_l2(
    const float* __restrict__ agg,
    const float* __restrict__ w_root2, const float* __restrict__ w_rel2,
    const float* __restrict__ b2,
    float* __restrict__ p2, float* __restrict__ out2, int n) {
  int i = blockIdx.x * 256 + threadIdx.x;
  if (i >= n) return;
  const float4* a4 = (const float4*)(agg + (size_t)i * HID);
  float h[HID];
#pragma unroll
  for (int q = 0; q < 4; ++q) {
    float4 v = a4[q];
    float t[4] = {v.x, v.y, v.z, v.w};
#pragma unroll
    for (int j = 0; j < 4; ++j)
      h[4*q + j] = t[j] > 0.f ? t[j] : expm1f(t[j]);
  }
#pragma unroll
  for (int c = 0; c < NCLS; ++c) {
    float sr = 0.f, so = b2[c];
#pragma unroll
    for (int k = 0; k < HID; ++k) {
      sr = fmaf(h[k], w_rel2[k * NCLS + c], sr);
      so = fmaf(h[k], w_root2[k * NCLS + c], so);
    }
    p2[(size_t)i * NCLS + c] = sr;
    out2[(size_t)i * NCLS + c] = so;
  }
}

// K5: in-place log_softmax over 7 classes.
__global__ __launch_bounds__(256) void k5_lsm(float* __restrict__ out, int n) {
  int i = blockIdx.x * 256 + threadIdx.x;
  if (i >= n) return;
  float v[NCLS];
  float* o = out + (size_t)i * NCLS;
#pragma unroll
  for (int c = 0; c < NCLS; ++c) v[c] = o[c];
  float m = v[0];
#pragma unroll
  for (int c = 1; c < NCLS; ++c) m = fmaxf(m, v[c]);
  float s = 0.f;
#pragma unroll
  for (int c = 0; c < NCLS; ++c) s += expf(v[c] - m);
  float l = logf(s);
#pragma unroll
  for (int c = 0; c < NCLS; ++c) o[c] = v[c] - m - l;
}

extern "C" void kernel_launch(void* const* d_in, const int* in_sizes, int n_in,
                              void* d_out, int out_size, void* d_ws, size_t ws_size,
                              hipStream_t stream) {
  const float* x       = (const float*)d_in[0];
  const int*   ei      = (const int*)  d_in[1];
  const float* w_root1 = (const float*)d_in[2];
  const float* w_rel1  = (const float*)d_in[3];
  const float* b_rel1  = (const float*)d_in[4];
  const float* w_root2 = (const float*)d_in[5];
  const float* w_rel2  = (const float*)d_in[6];
  const float* b_rel2  = (const float*)d_in[7];
  float* out = (float*)d_out;

  int n  = in_sizes[0] / FIN;   // 100000
  int nE = in_sizes[1] / 2;     // 3200000

  size_t seg = (size_t)n * HID;             // elems per slice buffer
  char* ws = (char*)d_ws;
  float* pbase = (float*)ws;                               // KS * seg f32
  float* abase = pbase + KS * seg;                         // KS * seg f32
  float* p2    = abase + KS * seg;                         // n*7 f32
  int*   hist  = (int*)(p2 + (size_t)n * NCLS);            // n
  int*   offs  = hist + n;                                 // n
  int*   cur   = offs + n;                                 // n
  int*   ssrc  = cur + n;                                  // nE

  int nbE = (nE + 255) / 256;
  int nbN = (n + 255) / 256;

  // edge bucketing (independent of GEMM; scheduler may overlap)
  k_zero<<<nbN, 256, 0, stream>>>(hist, n);
  k_hist<<<nbE, 256, 0, stream>>>(ei, hist, nE);
  k_scan<<<1, 1024, 0, stream>>>(hist, offs, cur, n);
  k_place<<<nbE, 256, 0, stream>>>(ei, cur, ssrc, nE);

  // layer 1 GEMM
  dim3 g1((n + BM - 1) / BM, KS);
  k1_gemm<<<g1, 256, 0, stream>>>(x, w_root1, w_rel1, b_rel1,
                                  pbase, abase, seg, n);
  int n4 = n * HID / 4;
  k_reduce<<<(n4 + 255) / 256, 256, 0, stream>>>(pbase, abase, seg, n4);

  // layer 1 aggregation (gather-reduce)
  long long t1 = (long long)n * 16;
  k_agg16<<<(int)((t1 + 255) / 256), 256, 0, stream>>>(ssrc, offs, hist, pbase, abase, n);

  // layer 2
  k3_l2<<<nbN, 256, 0, stream>>>(abase, w_root2, w_rel2, b_rel2, p2, out, n);
  long long t2 = (long long)n * 8;
  k_agg7<<<(int)((t2 + 255) / 256), 256, 0, stream>>>(ssrc, offs, hist, p2, out, n);

  k5_lsm<<<nbN, 256, 0, stream>>>(out, n);
}

// Round 5
// 594.807 us; speedup vs baseline: 1.6362x; 1.6362x over previous
//
#include <hip/hip_runtime.h>
#include <math.h>

#define FIN  1433
#define HID  16
#define NCLS 7
#define BM   128
#define BK   32
#define KS   4          // split-K slices
#define KT_TOTAL 45     // ceil(1433/32)

// ---------------- K1: split-K tiled dual GEMM ----------------
// C[n x 32] = x[n x 1433] @ [w_rel1 | w_root1]; grid (ceil(n/128), KS).
// Slice s accumulates its k-tile range into pbase/abase + s*seg.
// LDS x-tile XOR-swizzled (write (c,r) -> xs[c*128+(r^c)]); reads are
// float4 with static component unpermute. Register prefetch overlaps
// next tile's global loads with current tile's compute.
__global__ __launch_bounds__(256) void k1_gemm(
    const float* __restrict__ x,
    const float* __restrict__ w_root, const float* __restrict__ w_rel,
    const float* __restrict__ b_rel,
    float* __restrict__ pbase, float* __restrict__ abase,
    size_t seg_elems, int n) {
  __shared__ float xs[BK * BM];
  __shared__ float ws[BK * 32];

  const int tid   = threadIdx.x;
  const int row0  = blockIdx.x * BM;
  const int slice = blockIdx.y;
  const int cg    = tid & 7;
  const int rg    = tid >> 3;
  const int c0    = cg * 4;
  const int r0    = rg * 4;

  const int kt_beg = (KT_TOTAL * slice) / KS;
  const int kt_end = (KT_TOTAL * (slice + 1)) / KS;

  float acc[4][4];
#pragma unroll
  for (int i = 0; i < 4; ++i)
#pragma unroll
    for (int j = 0; j < 4; ++j) acc[i][j] = 0.f;

  float xreg[16], wreg[4];
  auto prefetch = [&](int kt) {
    const int k0 = kt * BK;
#pragma unroll
    for (int i = 0; i < 16; ++i) {
      int idx = i * 256 + tid;
      int r = idx >> 5, c = idx & 31;
      int gr = row0 + r, gk = k0 + c;
      xreg[i] = (gr < n && gk < FIN) ? x[(size_t)gr * FIN + gk] : 0.f;
    }
#pragma unroll
    for (int i = 0; i < 4; ++i) {
      int idx = i * 256 + tid;
      int kk = idx >> 5, c = idx & 31;
      int gk = k0 + kk;
      float v = 0.f;
      if (gk < FIN) v = (c < HID) ? w_rel[gk * HID + c] : w_root[gk * HID + (c - HID)];
      wreg[i] = v;
    }
  };

  prefetch(kt_beg);
  for (int kt = kt_beg; kt < kt_end; ++kt) {
    __syncthreads();
#pragma unroll
    for (int i = 0; i < 16; ++i) {
      int idx = i * 256 + tid;
      int r = idx >> 5, c = idx & 31;
      xs[c * BM + (r ^ c)] = xreg[i];
    }
#pragma unroll
    for (int i = 0; i < 4; ++i) {
      int idx = i * 256 + tid;
      int kk = idx >> 5, c = idx & 31;
      ws[kk * 32 + c] = wreg[i];
    }
    __syncthreads();
    if (kt + 1 < kt_end) prefetch(kt + 1);
#pragma unroll
    for (int kk = 0; kk < BK; ++kk) {
      float4 xv = *(const float4*)&xs[kk * BM + ((r0 ^ kk) & ~3)];
      float4 wv = *(const float4*)&ws[kk * 32 + c0];
      float comp[4] = {xv.x, xv.y, xv.z, xv.w};
      const int p = kk & 3;
      float xa[4] = {comp[0 ^ p], comp[1 ^ p], comp[2 ^ p], comp[3 ^ p]};
      float wa[4] = {wv.x, wv.y, wv.z, wv.w};
#pragma unroll
      for (int i = 0; i < 4; ++i)
#pragma unroll
        for (int j = 0; j < 4; ++j)
          acc[i][j] = fmaf(xa[i], wa[j], acc[i][j]);
    }
  }

  float* __restrict__ p_out = pbase + (size_t)slice * seg_elems;
  float* __restrict__ a_out = abase + (size_t)slice * seg_elems;
  if (cg < 4) {
#pragma unroll
    for (int i = 0; i < 4; ++i) {
      int gr = row0 + r0 + i;
      if (gr < n) {
        float4 v = {acc[i][0], acc[i][1], acc[i][2], acc[i][3]};
        *(float4*)&p_out[(size_t)gr * HID + c0] = v;
      }
    }
  } else {
    const int cb = c0 - HID;
    float b0 = 0.f, b1 = 0.f, b2v = 0.f, b3 = 0.f;
    if (slice == 0) { b0 = b_rel[cb]; b1 = b_rel[cb+1]; b2v = b_rel[cb+2]; b3 = b_rel[cb+3]; }
#pragma unroll
    for (int i = 0; i < 4; ++i) {
      int gr = row0 + r0 + i;
      if (gr < n) {
        float4 v = {acc[i][0] + b0, acc[i][1] + b1, acc[i][2] + b2v, acc[i][3] + b3};
        *(float4*)&a_out[(size_t)gr * HID + cb] = v;
      }
    }
  }
}

// KR: sum KS split-K partials into slice 0 (float4 granularity).
__global__ __launch_bounds__(256) void k_reduce(
    float* __restrict__ pbase, float* __restrict__ abase,
    size_t seg_elems, int n4) {
  int i = blockIdx.x * 256 + threadIdx.x;
  if (i >= n4) return;
  size_t s4 = seg_elems / 4;
  float4 a = ((const float4*)pbase)[i];
  float4 c = ((const float4*)abase)[i];
#pragma unroll
  for (int s = 1; s < KS; ++s) {
    float4 b = ((const float4*)pbase)[i + s * s4];
    float4 d = ((const float4*)abase)[i + s * s4];
    a.x += b.x; a.y += b.y; a.z += b.z; a.w += b.w;
    c.x += d.x; c.y += d.y; c.z += d.z; c.w += d.w;
  }
  ((float4*)pbase)[i] = a;
  ((float4*)abase)[i] = c;
}

// K2: scatter-add 16-wide. 16 threads per edge, 1 scalar atomic each.
__global__ __launch_bounds__(256) void k2_scatter16(
    const int* __restrict__ ei, const float* __restrict__ p,
    float* __restrict__ agg, int nE) {
  long long tid = (long long)blockIdx.x * 256 + threadIdx.x;
  if (tid >= (long long)nE * HID) return;
  int e = (int)(tid >> 4), f = (int)(tid & 15);
  int s = ei[e], d = ei[nE + e];
  atomicAdd(agg + (size_t)d * HID + f, p[(size_t)s * HID + f]);
}

// K3: ELU + dual 16x7 projection; out2 gets root part + bias.
__global__ __launch_bounds__(256) void k3_l2(
    const float* __restrict__ agg,
    const float* __restrict__ w_root2, const float* __restrict__ w_rel2,
    const float* __restrict__ b2,
    float* __restrict__ p2, float* __restrict__ out2, int n) {
  int i = blockIdx.x * 256 + threadIdx.x;
  if (i >= n) return;
  const float4* a4 = (const float4*)(agg + (size_t)i * HID);
  float h[HID];
#pragma unroll
  for (int q = 0; q < 4; ++q) {
    float4 v = a4[q];
    float t[4] = {v.x, v.y, v.z, v.w};
#pragma unroll
    for (int j = 0; j < 4; ++j)
      h[4*q + j] = t[j] > 0.f ? t[j] : expm1f(t[j]);
  }
#pragma unroll
  for (int c = 0; c < NCLS; ++c) {
    float sr = 0.f, so = b2[c];
#pragma unroll
    for (int k = 0; k < HID; ++k) {
      sr = fmaf(h[k], w_rel2[k * NCLS + c], sr);
      so = fmaf(h[k], w_root2[k * NCLS + c], so);
    }
    p2[(size_t)i * NCLS + c] = sr;
    out2[(size_t)i * NCLS + c] = so;
  }
}

// K4: scatter-add 7-wide. 8 threads/edge, lane 7 idle.
__global__ __launch_bounds__(256) void k4_scatter7(
    const int* __restrict__ ei, const float* __restrict__ p,
    float* __restrict__ out2, int nE) {
  long long tid = (long long)blockIdx.x * 256 + threadIdx.x;
  int e = (int)(tid >> 3), f = (int)(tid & 7);
  if (e >= nE || f >= NCLS) return;
  int s = ei[e], d = ei[nE + e];
  atomicAdd(out2 + (size_t)d * NCLS + f, p[(size_t)s * NCLS + f]);
}

// K5: in-place log_softmax over 7 classes.
__global__ __launch_bounds__(256) void k5_lsm(float* __restrict__ out, int n) {
  int i = blockIdx.x * 256 + threadIdx.x;
  if (i >= n) return;
  float v[NCLS];
  float* o = out + (size_t)i * NCLS;
#pragma unroll
  for (int c = 0; c < NCLS; ++c) v[c] = o[c];
  float m = v[0];
#pragma unroll
  for (int c = 1; c < NCLS; ++c) m = fmaxf(m, v[c]);
  float s = 0.f;
#pragma unroll
  for (int c = 0; c < NCLS; ++c) s += expf(v[c] - m);
  float l = logf(s);
#pragma unroll
  for (int c = 0; c < NCLS; ++c) o[c] = v[c] - m - l;
}

extern "C" void kernel_launch(void* const* d_in, const int* in_sizes, int n_in,
                              void* d_out, int out_size, void* d_ws, size_t ws_size,
                              hipStream_t stream) {
  const float* x       = (const float*)d_in[0];
  const int*   ei      = (const int*)  d_in[1];
  const float* w_root1 = (const float*)d_in[2];
  const float* w_rel1  = (const float*)d_in[3];
  const float* b_rel1  = (const float*)d_in[4];
  const float* w_root2 = (const float*)d_in[5];
  const float* w_rel2  = (const float*)d_in[6];
  const float* b_rel2  = (const float*)d_in[7];
  float* out = (float*)d_out;

  int n  = in_sizes[0] / FIN;   // 100000
  int nE = in_sizes[1] / 2;     // 3200000

  size_t seg = (size_t)n * HID;             // elems per slice buffer
  char* ws = (char*)d_ws;
  float* pbase = (float*)ws;                               // KS * seg f32
  float* abase = pbase + KS * seg;                         // KS * seg f32
  float* p2    = abase + KS * seg;                         // n*7 f32

  int nbN = (n + 255) / 256;

  // layer 1 GEMM (split-K=4)
  dim3 g1((n + BM - 1) / BM, KS);
  k1_gemm<<<g1, 256, 0, stream>>>(x, w_root1, w_rel1, b_rel1,
                                  pbase, abase, seg, n);
  int n4 = n * HID / 4;
  k_reduce<<<(n4 + 255) / 256, 256, 0, stream>>>(pbase, abase, seg, n4);

  // layer 1 aggregation (atomic scatter, 16 lanes/edge)
  long long t2 = (long long)nE * HID;
  k2_scatter16<<<(int)((t2 + 255) / 256), 256, 0, stream>>>(ei, pbase, abase, nE);

  // layer 2
  k3_l2<<<nbN, 256, 0, stream>>>(abase, w_root2, w_rel2, b_rel2, p2, out, n);
  long long t4 = (long long)nE * 8;
  k4_scatter7<<<(int)((t4 + 255) / 256), 256, 0, stream>>>(ei, p2, out, nE);

  k5_lsm<<<nbN, 256, 0, stream>>>(out, n);
}